// Round 1
// baseline (9.689 us; speedup 1.0000x reference)
//
#include <hip/hip_runtime.h>
#include <hip/hip_bf16.h>
#include <math.h>

// Linear slab ODE, Euler dt=60, nt steps, save every step.
//   U' = U + DT*( fc*V + k0*TAx - k1*U)
//   V' = V + DT*(-fc*U + k0*TAy - k1*V)
// As complex z = U + iV:  z_{n+1} = w*z + B,  w = (1-DT*k1) - i*DT*fc,
// B = DT*k0*(TAx + i*TAy).  With z0 = 0:  z_n = B*(w^n - 1)/(w - 1).
// Each output step computed independently in fp64 (closed form), cast to fp32.

#define DT_SEC 60.0

__global__ void slab_closed_form_kernel(const float* __restrict__ pk,
                                        const float* __restrict__ TAx,
                                        const float* __restrict__ TAy,
                                        const float* __restrict__ fc,
                                        float* __restrict__ out,
                                        int nt) {
    int i = blockIdx.x * blockDim.x + threadIdx.x;
    if (i >= nt) return;
    const double n = (double)(i + 1);  // ys[i] is state after step i+1

    // Scalar setup (redundant per thread; a few hundred cycles, cached loads).
    const double k0 = exp((double)pk[0]);
    const double k1 = exp((double)pk[1]);
    const double a  = 1.0 - DT_SEC * k1;          // Re(w)
    const double c  = DT_SEC * (double)fc[0];     // -Im(w)
    const double bx = DT_SEC * k0 * (double)TAx[0];
    const double by = DT_SEC * k0 * (double)TAy[0];

    // w = a - i*c ;  w^n = exp(n*ln|w|) * (cos(n*th) + i*sin(n*th))
    const double lnr = 0.5 * log(a * a + c * c);
    const double th  = atan2(-c, a);
    const double rn  = exp(n * lnr);
    double sn, cn;
    sincos(n * th, &sn, &cn);
    const double wnr = rn * cn;
    const double wni = rn * sn;

    // P = B / (w - 1);  z_n = P * (w^n - 1)
    const double dr = a - 1.0;
    const double di = -c;
    const double d2 = dr * dr + di * di;

    double U, V;
    if (d2 > 0.0) {
        const double Pr = (bx * dr + by * di) / d2;
        const double Pi = (by * dr - bx * di) / d2;
        const double er = wnr - 1.0;
        U = Pr * er  - Pi * wni;
        V = Pr * wni + Pi * er;
    } else {
        // Degenerate w == 1 (k1 = fc = 0): z_n = n*B
        U = n * bx;
        V = n * by;
    }

    out[i]      = (float)U;   // Us
    out[nt + i] = (float)V;   // Vs
}

extern "C" void kernel_launch(void* const* d_in, const int* in_sizes, int n_in,
                              void* d_out, int out_size, void* d_ws, size_t ws_size,
                              hipStream_t stream) {
    const float* pk  = (const float*)d_in[0];  // [2]
    const float* TAx = (const float*)d_in[1];  // [1]
    const float* TAy = (const float*)d_in[2];  // [1]
    const float* fc  = (const float*)d_in[3];  // [1]
    // d_in[4] is nt (int), but out_size == 2*nt gives it host-side.
    (void)in_sizes; (void)n_in; (void)d_ws; (void)ws_size;

    const int nt = out_size / 2;
    float* out = (float*)d_out;

    const int block = 256;
    const int grid  = (nt + block - 1) / block;
    slab_closed_form_kernel<<<grid, block, 0, stream>>>(pk, TAx, TAy, fc, out, nt);
}

// Round 2
// 9.677 us; speedup vs baseline: 1.0013x; 1.0013x over previous
//
#include <hip/hip_runtime.h>
#include <hip/hip_bf16.h>
#include <math.h>

// Linear slab ODE, Euler dt=60, nt steps, save every step.
//   U' = U + DT*( fc*V + k0*TAx - k1*U)
//   V' = V + DT*(-fc*U + k0*TAy - k1*V)
// As complex z = U + iV:  z_{n+1} = w*z + B,  w = (1-DT*k1) - i*DT*fc,
// B = DT*k0*(TAx + i*TAy).  With z0 = 0:  z_n = B*(w^n - 1)/(w - 1).
// w^n computed per-thread by complex binary exponentiation in fp64
// (16 squarings for n<=40320) — no software fp64 transcendentals.

#define DT_SEC 60.0

__global__ void slab_closed_form_kernel(const float* __restrict__ pk,
                                        const float* __restrict__ TAx,
                                        const float* __restrict__ TAy,
                                        const float* __restrict__ fc,
                                        float* __restrict__ out,
                                        int nt) {
    int i = blockIdx.x * blockDim.x + threadIdx.x;
    if (i >= nt) return;

    // k0, k1 need only fp32-exp relative accuracy (~1e-7): error in k1
    // perturbs a=1-DT*k1 by ~1e-11, amplified to ~5e-7 relative in w^n.
    const double k0 = (double)__expf(pk[0]);
    const double k1 = (double)__expf(pk[1]);
    const double a  = 1.0 - DT_SEC * k1;          // Re(w)
    const double c  = DT_SEC * (double)fc[0];     // -Im(w)
    const double bx = DT_SEC * k0 * (double)TAx[0];
    const double by = DT_SEC * k0 * (double)TAy[0];

    // w^n by square-and-multiply (n = i+1, <= ~2^16 -> 16 iterations).
    unsigned e = (unsigned)(i + 1);
    double wr = a, wi = -c;      // running square: w^(2^k)
    double rr = 1.0, ri = 0.0;   // accumulated result
    while (e) {
        if (e & 1u) {
            const double tr = rr * wr - ri * wi;
            ri = rr * wi + ri * wr;
            rr = tr;
        }
        e >>= 1;
        if (e) {
            const double tr = wr * wr - wi * wi;
            wi = 2.0 * wr * wi;
            wr = tr;
        }
    }
    // rr + i*ri = w^n

    // P = B / (w - 1);  z_n = P * (w^n - 1)
    const double dr = a - 1.0;
    const double di = -c;
    const double d2 = dr * dr + di * di;

    double U, V;
    if (d2 > 0.0) {
        const double Pr = (bx * dr + by * di) / d2;
        const double Pi = (by * dr - bx * di) / d2;
        const double er = rr - 1.0;
        U = Pr * er - Pi * ri;
        V = Pr * ri + Pi * er;
    } else {
        // Degenerate w == 1 (k1 = fc = 0): z_n = n*B
        const double n = (double)(i + 1);
        U = n * bx;
        V = n * by;
    }

    out[i]      = (float)U;   // Us
    out[nt + i] = (float)V;   // Vs
}

extern "C" void kernel_launch(void* const* d_in, const int* in_sizes, int n_in,
                              void* d_out, int out_size, void* d_ws, size_t ws_size,
                              hipStream_t stream) {
    const float* pk  = (const float*)d_in[0];  // [2]
    const float* TAx = (const float*)d_in[1];  // [1]
    const float* TAy = (const float*)d_in[2];  // [1]
    const float* fc  = (const float*)d_in[3];  // [1]
    // d_in[4] is nt (int), but out_size == 2*nt gives it host-side.
    (void)in_sizes; (void)n_in; (void)d_ws; (void)ws_size;

    const int nt = out_size / 2;
    float* out = (float*)d_out;

    const int block = 256;
    const int grid  = (nt + block - 1) / block;
    slab_closed_form_kernel<<<grid, block, 0, stream>>>(pk, TAx, TAy, fc, out, nt);
}